// Round 12
// baseline (1237.297 us; speedup 1.0000x reference)
//
#include <hip/hip_runtime.h>
#include <cstdint>
#include <cstddef>

#define D_DIM 2048
#define D_HID 8192
#define N_TOK 8192

typedef int v4i __attribute__((ext_vector_type(4)));
typedef float v4f __attribute__((ext_vector_type(4)));

__device__ __forceinline__ void gload16(const void* g, void* l) {
  __builtin_amdgcn_global_load_lds(
      (__attribute__((address_space(1))) void*)(void*)(const_cast<void*>(g)),
      (__attribute__((address_space(3))) void*)(void*)(l), 16, 0, 0);
}

__device__ __forceinline__ unsigned pack4i8(int a, int b, int c, int d) {
  return (unsigned)(a & 255) | ((unsigned)(b & 255) << 8) |
         ((unsigned)(c & 255) << 16) | ((unsigned)(d & 255) << 24);
}

__device__ __forceinline__ int clampi(int v, int lo, int hi) {
  return v < lo ? lo : (v > hi ? hi : v);
}

// Branch-free exact-GELU via Abramowitz-Stegun 7.1.26 erf (|eps| <= 1.5e-7 abs).
__device__ __forceinline__ float gelu_fast(float c) {
  const float ax = fabsf(c) * 0.70710678118654752440f;
  const float t = 1.0f / fmaf(0.3275911f, ax, 1.0f);
  const float poly =
      t * fmaf(t, fmaf(t, fmaf(t, fmaf(t, 1.061405429f, -1.453152027f),
                               1.421413741f), -0.284496736f), 0.254829592f);
  const float e = 1.0f - poly * __expf(-ax * ax);
  const float es = copysignf(e, c);
  return 0.5f * c * (1.0f + es);
}

// ---------------- weight |w| sum (fixed-order f64, deterministic) ------------
__global__ __launch_bounds__(256) void wsum_k(const float* __restrict__ w1,
                                              const float* __restrict__ w2,
                                              double* __restrict__ part) {
  const int b = blockIdx.x;
  const float* w = (b < 1024) ? w1 : w2;
  const size_t base = (size_t)(b & 1023) * 16384;
  const int t = threadIdx.x;
  double s = 0.0;
  for (int i = 0; i < 64; ++i) s += fabs((double)w[base + (size_t)i * 256 + t]);
  __shared__ double red[256];
  red[t] = s;
  __syncthreads();
  for (int st = 128; st; st >>= 1) {
    if (t < st) red[t] += red[t + st];
    __syncthreads();
  }
  if (!t) part[b] = red[0];
}

__global__ __launch_bounds__(256) void wfinal_k(const double* __restrict__ part,
                                                double* __restrict__ swd,
                                                float* __restrict__ wsc) {
  __shared__ double red[256];
  const int t = threadIdx.x;
  for (int m = 0; m < 2; ++m) {
    double s = part[m * 1024 + t] + part[m * 1024 + 256 + t] +
               part[m * 1024 + 512 + t] + part[m * 1024 + 768 + t];
    red[t] = s;
    __syncthreads();
    for (int st = 128; st; st >>= 1) {
      if (t < st) red[t] += red[t + st];
      __syncthreads();
    }
    if (!t) {
      double mean = red[0] / 16777216.0;
      double m2 = fmax(mean, 1e-5);
      swd[m] = 1.0 / m2;
      wsc[m] = (float)m2;
    }
    __syncthreads();
  }
}

// ---------------- ternary weight quant (f64 decision, half-even) -------------
__global__ __launch_bounds__(256) void wquant_k(const float* __restrict__ w,
                                                int8_t* __restrict__ q,
                                                const double* __restrict__ swd, int idx) {
  const double s = swd[idx];
  const size_t i = ((size_t)blockIdx.x * 256 + threadIdx.x) * 4;
  const float4 v = *(const float4*)&w[i];
  const int q0 = clampi((int)__builtin_rint((double)v.x * s), -1, 1);
  const int q1 = clampi((int)__builtin_rint((double)v.y * s), -1, 1);
  const int q2 = clampi((int)__builtin_rint((double)v.z * s), -1, 1);
  const int q3 = clampi((int)__builtin_rint((double)v.w * s), -1, 1);
  *(unsigned*)&q[i] = pack4i8(q0, q1, q2, q3);
}

// ---------------- fused RMSNorm + per-token absmax int8 quant ----------------
__global__ __launch_bounds__(256) void rmsq_k(const float* __restrict__ x,
                                              const float* __restrict__ gamma,
                                              int8_t* __restrict__ qx,
                                              float* __restrict__ sxinv) {
  const int row = blockIdx.x, t = threadIdx.x;
  const float* xr = x + (size_t)row * D_DIM;
  const v4f v0 = __builtin_nontemporal_load((const v4f*)&xr[t * 4]);
  const v4f v1 = __builtin_nontemporal_load((const v4f*)&xr[1024 + t * 4]);
  double xs[8] = {v0[0], v0[1], v0[2], v0[3], v1[0], v1[1], v1[2], v1[3]};
  double ssq = 0.0;
#pragma unroll
  for (int j = 0; j < 8; ++j) ssq += xs[j] * xs[j];
  __shared__ double red[256];
  red[t] = ssq;
  __syncthreads();
  for (int st = 128; st; st >>= 1) {
    if (t < st) red[t] += red[t + st];
    __syncthreads();
  }
  const double rn = 1.0 / sqrt(red[0] / (double)D_DIM + 1e-6);
  __syncthreads();
  const float4 g0 = *(const float4*)&gamma[t * 4];
  const float4 g1 = *(const float4*)&gamma[1024 + t * 4];
  const double gs[8] = {g0.x, g0.y, g0.z, g0.w, g1.x, g1.y, g1.z, g1.w};
  double xn[8], am = 0.0;
#pragma unroll
  for (int j = 0; j < 8; ++j) {
    xn[j] = xs[j] * rn * gs[j];
    am = fmax(am, fabs(xn[j]));
  }
  red[t] = am;
  __syncthreads();
  for (int st = 128; st; st >>= 1) {
    if (t < st) red[t] = fmax(red[t], red[t + st]);
    __syncthreads();
  }
  const double amax = fmax(red[0], 1e-5);
  const double s = 127.0 / amax;
  int q[8];
#pragma unroll
  for (int j = 0; j < 8; ++j) q[j] = clampi((int)__builtin_rint(xn[j] * s), -128, 127);
  unsigned* qo = (unsigned*)(qx + (size_t)row * D_DIM);
  qo[t] = pack4i8(q[0], q[1], q[2], q[3]);
  qo[256 + t] = pack4i8(q[4], q[5], q[6], q[7]);
  if (!t) sxinv[row] = (float)(amax / 127.0);
}

// ---------------- per-token quant of gelu(h) (path A only) -------------------
__global__ __launch_bounds__(256) void hquant_k(const float* __restrict__ g,
                                                int8_t* __restrict__ qh,
                                                const unsigned* __restrict__ amaxh,
                                                float* __restrict__ shinv) {
  const int row = blockIdx.x, t = threadIdx.x;
  const float* gr = g + (size_t)row * D_HID;
  const double am = fmax((double)__uint_as_float(amaxh[row]), 1e-5);
  const double s = 127.0 / am;
  if (!t) shinv[row] = (float)(am / 127.0);
  unsigned* qo = (unsigned*)(qh + (size_t)row * D_HID);
#pragma unroll
  for (int j = 0; j < 8; ++j) {
    const v4f v = __builtin_nontemporal_load((const v4f*)&gr[j * 1024 + t * 4]);
    const int q0 = clampi((int)__builtin_rint((double)v[0] * s), -128, 127);
    const int q1 = clampi((int)__builtin_rint((double)v[1] * s), -128, 127);
    const int q2 = clampi((int)__builtin_rint((double)v[2] * s), -128, 127);
    const int q3 = clampi((int)__builtin_rint((double)v[3] * s), -128, 127);
    qo[j * 256 + t] = pack4i8(q0, q1, q2, q3);
  }
}

__global__ __launch_bounds__(256) void scalefix_k(const unsigned* __restrict__ amaxh,
                                                  float* __restrict__ shinv) {
  const int i = blockIdx.x * 256 + threadIdx.x;
  if (i < N_TOK)
    shinv[i] = (float)(fmax((double)__uint_as_float(amaxh[i]), 1e-5) / 127.0);
}

// ==== int8 NT GEMM, 128x128, BK=64: A via LDS dbuf, B DIRECT global->VGPR ====
// R11 audit: LDS port (~85 B/cyc/CU) was the largest pipe (55% of wall) and
// caps the old A+B-in-LDS structure at 56% of the i8 matrix ceiling. This
// kernel removes B from LDS: B fragments (col=lo, k-chunk=hi — layout verified
// by the passing LDS path) load per-lane global->VGPR, double-banked (bP/bQ),
// issued one tile early after STG_A. Tile-end wait is counted vmcnt(4): waits
// only the 2 A-staging DMAs (oldest), B loads stay in flight; the compiler's
// automatic waitcnt covers B's first use next tile. LDS/tile 48->24 KiB.
// B working set 8 KiB/tile is L1-resident; super-column order (R11, verified
// FETCH 437->92 MB) keeps B panels L2-local.
// EPI: 0 gelu rowmax; 1 gelu + f32 nt-store + rowmax; 2 dequant nt-store;
//      3 gelu + i8 quant store.
template <int EPI>
__global__ __launch_bounds__(256, 4) void gemm4_i8_k(const int8_t* __restrict__ A,
                                                     const int8_t* __restrict__ B, int K,
                                                     int NB_X,
                                                     float* __restrict__ Cf,
                                                     int8_t* __restrict__ Cq, int ldc,
                                                     const float* __restrict__ rowf,
                                                     const float* __restrict__ wscp,
                                                     unsigned* __restrict__ amax) {
  __shared__ __align__(16) int8_t Al[2][8192];
  const int tid = threadIdx.x;
  const int wave = tid >> 6, lane = tid & 63;
  const int hi = lane >> 4, lo = lane & 15;
  const int wr = (wave >> 1) * 64, wc = (wave & 1) * 64;

  const int nwg = gridDim.x;  // multiple of 8; super-columns of 8 col-panels
  const int bid = blockIdx.x;
  const int lid = (bid & 7) * (nwg >> 3) + (bid >> 3);  // XCD-contiguous
  const int grp = lid >> 9;
  const int rem = lid & 511;
  const int by = rem >> 3;
  const int bx = (grp << 3) | (rem & 7);
  const int row0 = by * 128, col0 = bx * 128;

  // A staging source: row (lane>>2), kchunk (lane&3)^((lane>>3)&3)
  const int srow = lane >> 2;
  const int skb = ((lane & 3) ^ ((lane >> 3) & 3)) * 16;
  const size_t aG0 = (size_t)(row0 + (2 * wave + 0) * 16 + srow) * K + skb;
  const size_t aG1 = (size_t)(row0 + (2 * wave + 1) * 16 + srow) * K + skb;
  const int ls0 = (2 * wave + 0) * 1024, ls1 = (2 * wave + 1) * 1024;
  // B direct fragment base: col = col0 + wc + n*16 + lo, k-bytes = hi*16
  const int8_t* Bbase = B + (size_t)(col0 + wc + lo) * K + hi * 16;
  const size_t bstride = (size_t)16 * K;  // n*16 columns
  const int NT = K >> 6;

  v4i acc[4][4];
#pragma unroll
  for (int m = 0; m < 4; ++m)
#pragma unroll
    for (int n = 0; n < 4; ++n) acc[m][n] = (v4i){0, 0, 0, 0};

  const int roff = lo * 64 + ((hi ^ ((lo >> 1) & 3)) * 16);
  const int asb = (wr >> 4);

#define STG_A(buf, T)                                                          \
  do {                                                                         \
    const size_t ko_ = (size_t)(T) * 64;                                       \
    gload16(A + aG0 + ko_, &Al[buf][ls0]);                                     \
    gload16(A + aG1 + ko_, &Al[buf][ls1]);                                     \
  } while (0)
#define LD_B(bank, T)                                                          \
  do {                                                                         \
    const size_t ko_ = (size_t)(T) * 64;                                       \
    bank##0 = *(const v4i*)&Bbase[ko_];                                        \
    bank##1 = *(const v4i*)&Bbase[bstride + ko_];                              \
    bank##2 = *(const v4i*)&Bbase[2 * bstride + ko_];                          \
    bank##3 = *(const v4i*)&Bbase[3 * bstride + ko_];                          \
  } while (0)
#define TILE(buf, bank, T)                                                     \
  do {                                                                         \
    v4i af0, af1, af2, af3;                                                    \
    af0 = *(const v4i*)&Al[buf][(asb + 0) * 1024 + roff];                      \
    af1 = *(const v4i*)&Al[buf][(asb + 1) * 1024 + roff];                      \
    af2 = *(const v4i*)&Al[buf][(asb + 2) * 1024 + roff];                      \
    af3 = *(const v4i*)&Al[buf][(asb + 3) * 1024 + roff];                      \
    __builtin_amdgcn_s_setprio(1);                                             \
    acc[0][0] = __builtin_amdgcn_mfma_i32_16x16x64_i8(af0, bank##0, acc[0][0], 0, 0, 0); \
    acc[0][1] = __builtin_amdgcn_mfma_i32_16x16x64_i8(af0, bank##1, acc[0][1], 0, 0, 0); \
    acc[0][2] = __builtin_amdgcn_mfma_i32_16x16x64_i8(af0, bank##2, acc[0][2], 0, 0, 0); \
    acc[0][3] = __builtin_amdgcn_mfma_i32_16x16x64_i8(af0, bank##3, acc[0][3], 0, 0, 0); \
    acc[1][0] = __builtin_amdgcn_mfma_i32_16x16x64_i8(af1, bank##0, acc[1][0], 0, 0, 0); \
    acc[1][1] = __builtin_amdgcn_mfma_i32_16x16x64_i8(af1, bank##1, acc[1][1], 0, 0, 0); \
    acc[1][2] = __builtin_amdgcn_mfma_i32_16x16x64_i8(af1, bank##2, acc[1][2], 0, 0, 0); \
    acc[1][3] = __builtin_amdgcn_mfma_i32_16x16x64_i8(af1, bank##3, acc[1][3], 0, 0, 0); \
    acc[2][0] = __builtin_amdgcn_mfma_i32_16x16x64_i8(af2, bank##0, acc[2][0], 0, 0, 0); \
    acc[2][1] = __builtin_amdgcn_mfma_i32_16x16x64_i8(af2, bank##1, acc[2][1], 0, 0, 0); \
    acc[2][2] = __builtin_amdgcn_mfma_i32_16x16x64_i8(af2, bank##2, acc[2][2], 0, 0, 0); \
    acc[2][3] = __builtin_amdgcn_mfma_i32_16x16x64_i8(af2, bank##3, acc[2][3], 0, 0, 0); \
    acc[3][0] = __builtin_amdgcn_mfma_i32_16x16x64_i8(af3, bank##0, acc[3][0], 0, 0, 0); \
    acc[3][1] = __builtin_amdgcn_mfma_i32_16x16x64_i8(af3, bank##1, acc[3][1], 0, 0, 0); \
    acc[3][2] = __builtin_amdgcn_mfma_i32_16x16x64_i8(af3, bank##2, acc[3][2], 0, 0, 0); \
    acc[3][3] = __builtin_amdgcn_mfma_i32_16x16x64_i8(af3, bank##3, acc[3][3], 0, 0, 0); \
    __builtin_amdgcn_s_setprio(0);                                             \
  } while (0)

  v4i bP0, bP1, bP2, bP3, bQ0, bQ1, bQ2, bQ3;

  // prologue: stage A(0), load B(0)->P; counted wait (A's 2 DMAs are oldest)
  STG_A(0, 0);
  LD_B(bP, 0);
  asm volatile("s_waitcnt vmcnt(4)" ::: "memory");
  __syncthreads();

  const int NH = NT >> 1;  // NT even (32 or 128)
#pragma unroll 1
  for (int it = 0; it < NH; ++it) {
    const int t0 = 2 * it, t1 = 2 * it + 1;
    // tile t0: buf0 + bank P; prefetch A(t1)->buf1, B(t1)->Q
    STG_A(1, t1);
    LD_B(bQ, t1);
    TILE(0, bP, t0);
    asm volatile("s_waitcnt vmcnt(4)" ::: "memory");
    __syncthreads();
    // tile t1: buf1 + bank Q; prefetch A(t1+1)->buf0, B(t1+1)->P
    if (t1 + 1 < NT) {
      STG_A(0, t1 + 1);
      LD_B(bP, t1 + 1);
    }
    TILE(1, bQ, t1);
    asm volatile("s_waitcnt vmcnt(4)" ::: "memory");
    __syncthreads();
  }
#undef STG_A
#undef LD_B
#undef TILE

  // ---- epilogue ----
  const float mw = wscp[0];
#pragma unroll
  for (int m = 0; m < 4; ++m) {
#pragma unroll
    for (int r = 0; r < 4; ++r) {
      const int grow = row0 + wr + m * 16 + hi * 4 + r;
      const float f = rowf[grow] * mw;
      if constexpr (EPI == 0 || EPI == 1) {
        float rmax = 0.f;
#pragma unroll
        for (int n = 0; n < 4; ++n) {
          const int gcol = col0 + wc + n * 16 + lo;
          const float c = (float)acc[m][n][r] * f;
          const float gv = gelu_fast(c);
          if constexpr (EPI == 1)
            __builtin_nontemporal_store(gv, &Cf[(size_t)grow * ldc + gcol]);
          rmax = fmaxf(rmax, fabsf(gv));
        }
#pragma unroll
        for (int sh = 1; sh < 16; sh <<= 1) rmax = fmaxf(rmax, __shfl_xor(rmax, sh));
        if (lo == 0) atomicMax(&amax[grow], __float_as_uint(rmax));
      } else if constexpr (EPI == 3) {
        const double s = 127.0 / fmax((double)__uint_as_float(amax[grow]), 1e-5);
#pragma unroll
        for (int n = 0; n < 4; ++n) {
          const int gcol = col0 + wc + n * 16 + lo;
          const float c = (float)acc[m][n][r] * f;
          const float gv = gelu_fast(c);
          Cq[(size_t)grow * ldc + gcol] =
              (int8_t)clampi((int)__builtin_rint((double)gv * s), -128, 127);
        }
      } else {
#pragma unroll
        for (int n = 0; n < 4; ++n) {
          const int gcol = col0 + wc + n * 16 + lo;
          __builtin_nontemporal_store((float)acc[m][n][r] * f,
                                      &Cf[(size_t)grow * ldc + gcol]);
        }
      }
    }
  }
}

__global__ void fill_k(float* p, int n, float v) {
  int i = blockIdx.x * 256 + threadIdx.x;
  if (i < n) p[i] = v;
}

extern "C" void kernel_launch(void* const* d_in, const int* in_sizes, int n_in, void* d_out,
                              int out_size, void* d_ws, size_t ws_size, hipStream_t stream) {
  const float* x = (const float*)d_in[0];
  const float* w1 = (const float*)d_in[1];
  const float* w2 = (const float*)d_in[2];
  const float* gamma = (const float*)d_in[3];
  float* out = (float*)d_out;
  char* ws = (char*)d_ws;

  const size_t SQX = (size_t)N_TOK * D_DIM;
  const size_t SQW1 = (size_t)D_HID * D_DIM;
  const size_t SQW2 = (size_t)D_DIM * D_HID;
  const size_t SQH = (size_t)N_TOK * D_HID;
  const size_t SG = (size_t)N_TOK * D_HID * 4;

  size_t off = 0;
  int8_t* qx = (int8_t*)(ws + off);  off += SQX;
  int8_t* qw1 = (int8_t*)(ws + off); off += SQW1;
  int8_t* qw2 = (int8_t*)(ws + off); off += SQW2;
  int8_t* qh = (int8_t*)(ws + off);  off += SQH;
  float* sxinv = (float*)(ws + off);       off += (size_t)N_TOK * 4;
  unsigned* amaxh = (unsigned*)(ws + off); off += (size_t)N_TOK * 4;
  float* shinv = (float*)(ws + off);       off += (size_t)N_TOK * 4;
  double* wpart = (double*)(ws + off);     off += 2048 * 8;
  double* swd = (double*)(ws + off);       off += 2 * 8;
  float* wsc = (float*)(ws + off);         off += 2 * 4;
  const size_t needB = off;
  float* g = (float*)(ws + off);
  const size_t needA = off + SG;

  if (ws_size < needB) {
    const float v = 100000.0f + (float)(ws_size >> 20);
    fill_k<<<(out_size + 255) / 256, 256, 0, stream>>>(out, out_size, v);
    return;
  }
  const bool pathA = (ws_size >= needA);

  hipMemsetAsync(amaxh, 0, (size_t)N_TOK * 4, stream);
  wsum_k<<<2048, 256, 0, stream>>>(w1, w2, wpart);
  wfinal_k<<<1, 256, 0, stream>>>(wpart, swd, wsc);
  wquant_k<<<16384, 256, 0, stream>>>(w1, qw1, swd, 0);
  wquant_k<<<16384, 256, 0, stream>>>(w2, qw2, swd, 1);
  rmsq_k<<<N_TOK, 256, 0, stream>>>(x, gamma, qx, sxinv);

  const int nwg1 = (N_TOK / 128) * (D_HID / 128);  // 4096
  const int nwg2 = (N_TOK / 128) * (D_DIM / 128);  // 1024
  if (pathA) {
    gemm4_i8_k<1><<<nwg1, 256, 0, stream>>>(qx, qw1, D_DIM, D_HID / 128, g, nullptr,
                                            D_HID, sxinv, wsc + 0, amaxh);
    hquant_k<<<N_TOK, 256, 0, stream>>>(g, qh, amaxh, shinv);
  } else {
    gemm4_i8_k<0><<<nwg1, 256, 0, stream>>>(qx, qw1, D_DIM, D_HID / 128, nullptr, nullptr,
                                            D_HID, sxinv, wsc + 0, amaxh);
    scalefix_k<<<(N_TOK + 255) / 256, 256, 0, stream>>>(amaxh, shinv);
    gemm4_i8_k<3><<<nwg1, 256, 0, stream>>>(qx, qw1, D_DIM, D_HID / 128, nullptr, qh,
                                            D_HID, sxinv, wsc + 0, amaxh);
  }
  gemm4_i8_k<2><<<nwg2, 256, 0, stream>>>(qh, qw2, D_HID, D_DIM / 128, out, nullptr,
                                          D_DIM, shinv, wsc + 1, nullptr);
}

// Round 13
// 469.785 us; speedup vs baseline: 2.6337x; 2.6337x over previous
//
#include <hip/hip_runtime.h>
#include <cstdint>
#include <cstddef>

#define D_DIM 2048
#define D_HID 8192
#define N_TOK 8192

typedef int v4i __attribute__((ext_vector_type(4)));
typedef float v4f __attribute__((ext_vector_type(4)));
typedef _Float16 v8h __attribute__((ext_vector_type(8)));

__device__ __forceinline__ void gload16(const void* g, void* l) {
  __builtin_amdgcn_global_load_lds(
      (__attribute__((address_space(1))) void*)(void*)(const_cast<void*>(g)),
      (__attribute__((address_space(3))) void*)(void*)(l), 16, 0, 0);
}

__device__ __forceinline__ unsigned pack4i8(int a, int b, int c, int d) {
  return (unsigned)(a & 255) | ((unsigned)(b & 255) << 8) |
         ((unsigned)(c & 255) << 16) | ((unsigned)(d & 255) << 24);
}

__device__ __forceinline__ int clampi(int v, int lo, int hi) {
  return v < lo ? lo : (v > hi ? hi : v);
}

// Branch-free exact-GELU via Abramowitz-Stegun 7.1.26 erf (|eps| <= 1.5e-7 abs).
__device__ __forceinline__ float gelu_fast(float c) {
  const float ax = fabsf(c) * 0.70710678118654752440f;
  const float t = 1.0f / fmaf(0.3275911f, ax, 1.0f);
  const float poly =
      t * fmaf(t, fmaf(t, fmaf(t, fmaf(t, 1.061405429f, -1.453152027f),
                               1.421413741f), -0.284496736f), 0.254829592f);
  const float e = 1.0f - poly * __expf(-ax * ax);
  const float es = copysignf(e, c);
  return 0.5f * c * (1.0f + es);
}

// ---------------- weight |w| sum (fixed-order f64, deterministic) ------------
__global__ __launch_bounds__(256) void wsum_k(const float* __restrict__ w1,
                                              const float* __restrict__ w2,
                                              double* __restrict__ part) {
  const int b = blockIdx.x;
  const float* w = (b < 1024) ? w1 : w2;
  const size_t base = (size_t)(b & 1023) * 16384;
  const int t = threadIdx.x;
  double s = 0.0;
  for (int i = 0; i < 64; ++i) s += fabs((double)w[base + (size_t)i * 256 + t]);
  __shared__ double red[256];
  red[t] = s;
  __syncthreads();
  for (int st = 128; st; st >>= 1) {
    if (t < st) red[t] += red[t + st];
    __syncthreads();
  }
  if (!t) part[b] = red[0];
}

__global__ __launch_bounds__(256) void wfinal_k(const double* __restrict__ part,
                                                double* __restrict__ swd,
                                                float* __restrict__ wsc) {
  __shared__ double red[256];
  const int t = threadIdx.x;
  for (int m = 0; m < 2; ++m) {
    double s = part[m * 1024 + t] + part[m * 1024 + 256 + t] +
               part[m * 1024 + 512 + t] + part[m * 1024 + 768 + t];
    red[t] = s;
    __syncthreads();
    for (int st = 128; st; st >>= 1) {
      if (t < st) red[t] += red[t + st];
      __syncthreads();
    }
    if (!t) {
      double mean = red[0] / 16777216.0;
      double m2 = fmax(mean, 1e-5);
      swd[m] = 1.0 / m2;
      wsc[m] = (float)m2;
    }
    __syncthreads();
  }
}

// ---------------- ternary weight quant (f64 decision, half-even) -------------
__global__ __launch_bounds__(256) void wquant_k(const float* __restrict__ w,
                                                int8_t* __restrict__ q,
                                                const double* __restrict__ swd, int idx) {
  const double s = swd[idx];
  const size_t i = ((size_t)blockIdx.x * 256 + threadIdx.x) * 4;
  const float4 v = *(const float4*)&w[i];
  const int q0 = clampi((int)__builtin_rint((double)v.x * s), -1, 1);
  const int q1 = clampi((int)__builtin_rint((double)v.y * s), -1, 1);
  const int q2 = clampi((int)__builtin_rint((double)v.z * s), -1, 1);
  const int q3 = clampi((int)__builtin_rint((double)v.w * s), -1, 1);
  *(unsigned*)&q[i] = pack4i8(q0, q1, q2, q3);
}

// ---------------- fused RMSNorm + per-token absmax int8 quant ----------------
__global__ __launch_bounds__(256) void rmsq_k(const float* __restrict__ x,
                                              const float* __restrict__ gamma,
                                              int8_t* __restrict__ qx,
                                              float* __restrict__ sxinv) {
  const int row = blockIdx.x, t = threadIdx.x;
  const float* xr = x + (size_t)row * D_DIM;
  const v4f v0 = __builtin_nontemporal_load((const v4f*)&xr[t * 4]);
  const v4f v1 = __builtin_nontemporal_load((const v4f*)&xr[1024 + t * 4]);
  double xs[8] = {v0[0], v0[1], v0[2], v0[3], v1[0], v1[1], v1[2], v1[3]};
  double ssq = 0.0;
#pragma unroll
  for (int j = 0; j < 8; ++j) ssq += xs[j] * xs[j];
  __shared__ double red[256];
  red[t] = ssq;
  __syncthreads();
  for (int st = 128; st; st >>= 1) {
    if (t < st) red[t] += red[t + st];
    __syncthreads();
  }
  const double rn = 1.0 / sqrt(red[0] / (double)D_DIM + 1e-6);
  __syncthreads();
  const float4 g0 = *(const float4*)&gamma[t * 4];
  const float4 g1 = *(const float4*)&gamma[1024 + t * 4];
  const double gs[8] = {g0.x, g0.y, g0.z, g0.w, g1.x, g1.y, g1.z, g1.w};
  double xn[8], am = 0.0;
#pragma unroll
  for (int j = 0; j < 8; ++j) {
    xn[j] = xs[j] * rn * gs[j];
    am = fmax(am, fabs(xn[j]));
  }
  red[t] = am;
  __syncthreads();
  for (int st = 128; st; st >>= 1) {
    if (t < st) red[t] = fmax(red[t], red[t + st]);
    __syncthreads();
  }
  const double amax = fmax(red[0], 1e-5);
  const double s = 127.0 / amax;
  int q[8];
#pragma unroll
  for (int j = 0; j < 8; ++j) q[j] = clampi((int)__builtin_rint(xn[j] * s), -128, 127);
  unsigned* qo = (unsigned*)(qx + (size_t)row * D_DIM);
  qo[t] = pack4i8(q[0], q[1], q[2], q[3]);
  qo[256 + t] = pack4i8(q[4], q[5], q[6], q[7]);
  if (!t) sxinv[row] = (float)(amax / 127.0);
}

// ---------------- per-token quant of f16 gelu(h) (path A16) ------------------
__global__ __launch_bounds__(256) void hquant16_k(const _Float16* __restrict__ g16,
                                                  int8_t* __restrict__ qh,
                                                  const unsigned* __restrict__ amaxh,
                                                  float* __restrict__ shinv) {
  const int row = blockIdx.x, t = threadIdx.x;
  const _Float16* gr = g16 + (size_t)row * D_HID;
  const double am = fmax((double)__uint_as_float(amaxh[row]), 1e-5);
  const double s = 127.0 / am;
  if (!t) shinv[row] = (float)(am / 127.0);
  unsigned* qo = (unsigned*)(qh + (size_t)row * D_HID);
#pragma unroll
  for (int j = 0; j < 4; ++j) {
    const v8h v = __builtin_nontemporal_load((const v8h*)&gr[j * 2048 + t * 8]);
    int q[8];
#pragma unroll
    for (int e = 0; e < 8; ++e)
      q[e] = clampi((int)__builtin_rint((double)(float)v[e] * s), -128, 127);
    qo[j * 512 + t * 2 + 0] = pack4i8(q[0], q[1], q[2], q[3]);
    qo[j * 512 + t * 2 + 1] = pack4i8(q[4], q[5], q[6], q[7]);
  }
}

__global__ __launch_bounds__(256) void scalefix_k(const unsigned* __restrict__ amaxh,
                                                  float* __restrict__ shinv) {
  const int i = blockIdx.x * 256 + threadIdx.x;
  if (i < N_TOK)
    shinv[i] = (float)(fmax((double)__uint_as_float(amaxh[i]), 1e-5) / 127.0);
}

// ==== int8 NT GEMM, 128x128, BK=64, dbuf 2-phase, 4 blocks/CU, L2-local ======
// R11-verified structure (221 us, MfmaUtil 28%, conflicts 0, FETCH 92 MB):
// A+B staged in LDS via conflict-free [kslot-XOR] subblocks, coalesced
// global_load_lds source, super-column XCD-contiguous block order.
// EPI: 0 gelu rowmax; 1 gelu + f32 nt-store + rowmax; 2 dequant nt-store;
//      3 gelu + i8 quant store; 4 gelu + f16 nt-store + rowmax (path A16).
template <int EPI>
__global__ __launch_bounds__(256, 4) void gemm4_i8_k(const int8_t* __restrict__ A,
                                                     const int8_t* __restrict__ B, int K,
                                                     int NB_X,
                                                     float* __restrict__ Cf,
                                                     _Float16* __restrict__ Ch,
                                                     int8_t* __restrict__ Cq, int ldc,
                                                     const float* __restrict__ rowf,
                                                     const float* __restrict__ wscp,
                                                     unsigned* __restrict__ amax) {
  __shared__ __align__(16) int8_t Al[2][8192];
  __shared__ __align__(16) int8_t Bl[2][8192];
  const int tid = threadIdx.x;
  const int wave = tid >> 6, lane = tid & 63;
  const int hi = lane >> 4, lo = lane & 15;
  const int wr = (wave >> 1) * 64, wc = (wave & 1) * 64;

  const int nwg = gridDim.x;  // multiple of 8; super-columns of 8 col-panels
  const int bid = blockIdx.x;
  const int lid = (bid & 7) * (nwg >> 3) + (bid >> 3);  // XCD-contiguous
  const int grp = lid >> 9;
  const int rem = lid & 511;
  const int by = rem >> 3;
  const int bx = (grp << 3) | (rem & 7);
  const int row0 = by * 128, col0 = bx * 128;

  // staging source: row (lane>>2), kchunk (lane&3)^((lane>>3)&3)
  const int srow = lane >> 2;
  const int skb = ((lane & 3) ^ ((lane >> 3) & 3)) * 16;
  const size_t aG0 = (size_t)(row0 + (2 * wave + 0) * 16 + srow) * K + skb;
  const size_t aG1 = (size_t)(row0 + (2 * wave + 1) * 16 + srow) * K + skb;
  const size_t bG0 = (size_t)(col0 + (2 * wave + 0) * 16 + srow) * K + skb;
  const size_t bG1 = (size_t)(col0 + (2 * wave + 1) * 16 + srow) * K + skb;
  const int ls0 = (2 * wave + 0) * 1024, ls1 = (2 * wave + 1) * 1024;
  const int NT = K >> 6;

  v4i acc[4][4];
#pragma unroll
  for (int m = 0; m < 4; ++m)
#pragma unroll
    for (int n = 0; n < 4; ++n) acc[m][n] = (v4i){0, 0, 0, 0};

  const int roff = lo * 64 + ((hi ^ ((lo >> 1) & 3)) * 16);
  const int asb = (wr >> 4);
  const int bsb = (wc >> 4);

#define STG(buf, T)                                                            \
  do {                                                                         \
    const size_t ko_ = (size_t)(T) * 64;                                       \
    gload16(A + aG0 + ko_, &Al[buf][ls0]);                                     \
    gload16(A + aG1 + ko_, &Al[buf][ls1]);                                     \
    gload16(B + bG0 + ko_, &Bl[buf][ls0]);                                     \
    gload16(B + bG1 + ko_, &Bl[buf][ls1]);                                     \
  } while (0)

  // prologue
  STG(0, 0);
  asm volatile("s_waitcnt vmcnt(0)" ::: "memory");
  __syncthreads();

  int buf = 0;
#pragma unroll 1
  for (int t = 0; t < NT; ++t) {
    if (t + 1 < NT) STG(buf ^ 1, t + 1);  // issue-early
    v4i af[4], bf[4];
#pragma unroll
    for (int m = 0; m < 4; ++m) af[m] = *(const v4i*)&Al[buf][(asb + m) * 1024 + roff];
#pragma unroll
    for (int n = 0; n < 4; ++n) bf[n] = *(const v4i*)&Bl[buf][(bsb + n) * 1024 + roff];
    __builtin_amdgcn_s_setprio(1);
#pragma unroll
    for (int m = 0; m < 4; ++m)
#pragma unroll
      for (int n = 0; n < 4; ++n)
        acc[m][n] = __builtin_amdgcn_mfma_i32_16x16x64_i8(af[m], bf[n], acc[m][n], 0, 0, 0);
    __builtin_amdgcn_s_setprio(0);
    asm volatile("s_waitcnt vmcnt(0)" ::: "memory");  // wait-late (absorbed)
    __syncthreads();
    buf ^= 1;
  }
#undef STG

  // ---- epilogue ----
  const float mw = wscp[0];
#pragma unroll
  for (int m = 0; m < 4; ++m) {
#pragma unroll
    for (int r = 0; r < 4; ++r) {
      const int grow = row0 + wr + m * 16 + hi * 4 + r;
      const float f = rowf[grow] * mw;
      if constexpr (EPI == 0 || EPI == 1 || EPI == 4) {
        float rmax = 0.f;
#pragma unroll
        for (int n = 0; n < 4; ++n) {
          const int gcol = col0 + wc + n * 16 + lo;
          const float c = (float)acc[m][n][r] * f;
          const float gv = gelu_fast(c);
          if constexpr (EPI == 1)
            __builtin_nontemporal_store(gv, &Cf[(size_t)grow * ldc + gcol]);
          if constexpr (EPI == 4)
            __builtin_nontemporal_store((_Float16)gv, &Ch[(size_t)grow * ldc + gcol]);
          rmax = fmaxf(rmax, fabsf(gv));
        }
#pragma unroll
        for (int sh = 1; sh < 16; sh <<= 1) rmax = fmaxf(rmax, __shfl_xor(rmax, sh));
        if (lo == 0) atomicMax(&amax[grow], __float_as_uint(rmax));
      } else if constexpr (EPI == 3) {
        const double s = 127.0 / fmax((double)__uint_as_float(amax[grow]), 1e-5);
#pragma unroll
        for (int n = 0; n < 4; ++n) {
          const int gcol = col0 + wc + n * 16 + lo;
          const float c = (float)acc[m][n][r] * f;
          const float gv = gelu_fast(c);
          Cq[(size_t)grow * ldc + gcol] =
              (int8_t)clampi((int)__builtin_rint((double)gv * s), -128, 127);
        }
      } else {
#pragma unroll
        for (int n = 0; n < 4; ++n) {
          const int gcol = col0 + wc + n * 16 + lo;
          __builtin_nontemporal_store((float)acc[m][n][r] * f,
                                      &Cf[(size_t)grow * ldc + gcol]);
        }
      }
    }
  }
}

__global__ void fill_k(float* p, int n, float v) {
  int i = blockIdx.x * 256 + threadIdx.x;
  if (i < n) p[i] = v;
}

extern "C" void kernel_launch(void* const* d_in, const int* in_sizes, int n_in, void* d_out,
                              int out_size, void* d_ws, size_t ws_size, hipStream_t stream) {
  const float* x = (const float*)d_in[0];
  const float* w1 = (const float*)d_in[1];
  const float* w2 = (const float*)d_in[2];
  const float* gamma = (const float*)d_in[3];
  float* out = (float*)d_out;
  char* ws = (char*)d_ws;

  const size_t SQX = (size_t)N_TOK * D_DIM;
  const size_t SQW1 = (size_t)D_HID * D_DIM;
  const size_t SQW2 = (size_t)D_DIM * D_HID;
  const size_t SQH = (size_t)N_TOK * D_HID;
  const size_t SG16 = (size_t)N_TOK * D_HID * 2;  // 128 MiB f16 g

  size_t off = 0;
  int8_t* qx = (int8_t*)(ws + off);  off += SQX;
  int8_t* qw1 = (int8_t*)(ws + off); off += SQW1;
  int8_t* qw2 = (int8_t*)(ws + off); off += SQW2;
  int8_t* qh = (int8_t*)(ws + off);  off += SQH;
  float* sxinv = (float*)(ws + off);       off += (size_t)N_TOK * 4;
  unsigned* amaxh = (unsigned*)(ws + off); off += (size_t)N_TOK * 4;
  float* shinv = (float*)(ws + off);       off += (size_t)N_TOK * 4;
  double* wpart = (double*)(ws + off);     off += 2048 * 8;
  double* swd = (double*)(ws + off);       off += 2 * 8;
  float* wsc = (float*)(ws + off);         off += 2 * 4;
  off = (off + 255) & ~(size_t)255;
  const size_t needB = off;
  _Float16* g16 = (_Float16*)(ws + off);
  const size_t needA16 = off + SG16;

  if (ws_size < needB) {
    const float v = 100000.0f + (float)(ws_size >> 20);
    fill_k<<<(out_size + 255) / 256, 256, 0, stream>>>(out, out_size, v);
    return;
  }
  const bool pathA16 = (ws_size >= needA16);

  hipMemsetAsync(amaxh, 0, (size_t)N_TOK * 4, stream);
  wsum_k<<<2048, 256, 0, stream>>>(w1, w2, wpart);
  wfinal_k<<<1, 256, 0, stream>>>(wpart, swd, wsc);
  wquant_k<<<16384, 256, 0, stream>>>(w1, qw1, swd, 0);
  wquant_k<<<16384, 256, 0, stream>>>(w2, qw2, swd, 1);
  rmsq_k<<<N_TOK, 256, 0, stream>>>(x, gamma, qx, sxinv);

  const int nwg1 = (N_TOK / 128) * (D_HID / 128);  // 4096
  const int nwg2 = (N_TOK / 128) * (D_DIM / 128);  // 1024
  if (pathA16) {
    gemm4_i8_k<4><<<nwg1, 256, 0, stream>>>(qx, qw1, D_DIM, D_HID / 128, nullptr, g16,
                                            nullptr, D_HID, sxinv, wsc + 0, amaxh);
    hquant16_k<<<N_TOK, 256, 0, stream>>>(g16, qh, amaxh, shinv);
  } else {
    gemm4_i8_k<0><<<nwg1, 256, 0, stream>>>(qx, qw1, D_DIM, D_HID / 128, nullptr, nullptr,
                                            nullptr, D_HID, sxinv, wsc + 0, amaxh);
    scalefix_k<<<(N_TOK + 255) / 256, 256, 0, stream>>>(amaxh, shinv);
    gemm4_i8_k<3><<<nwg1, 256, 0, stream>>>(qx, qw1, D_DIM, D_HID / 128, nullptr, nullptr,
                                            qh, D_HID, sxinv, wsc + 0, amaxh);
  }
  gemm4_i8_k<2><<<nwg2, 256, 0, stream>>>(qh, qw2, D_HID, D_DIM / 128, out, nullptr,
                                          nullptr, D_DIM, shinv, wsc + 1, nullptr);
}